// Round 12
// baseline (194.849 us; speedup 1.0000x reference)
//
#include <hip/hip_runtime.h>
#include <stdint.h>

#define CIN 256
#define FDIM 128
#define NSP 4096
#define EPS 1e-5f

typedef __attribute__((ext_vector_type(8))) short short8;
typedef __attribute__((ext_vector_type(4))) float f32x4;
typedef __attribute__((ext_vector_type(16))) float f32x16;

__device__ __forceinline__ short f2bf(float f) {
  union { float f; uint32_t u; } v; v.f = f;
  uint32_t r = v.u + 0x7fffu + ((v.u >> 16) & 1u);
  return (short)(r >> 16);
}
__device__ __forceinline__ float bf2f(short h) {
  union { uint32_t u; float f; } v; v.u = ((uint32_t)(uint16_t)h) << 16;
  return v.f;
}

// ---------------- tiny prep: weights -> FRAG-MAJOR bf16, zero sums ----------------
__global__ void prep_w(const float* __restrict__ Wg, const float* __restrict__ Wt,
                       const float* __restrict__ Wp, const float* __restrict__ Wz,
                       short* __restrict__ Wbf, short* __restrict__ Wzbf,
                       float* __restrict__ sums) {
  int u = blockIdx.x * 256 + threadIdx.x;
  if (u < 8 && blockIdx.x == 0) sums[u] = 0.f;
  if (u < 12288) {
    int p = u >> 12;
    int rem = u & 4095;
    int ftg = rem >> 9, s = (rem >> 6) & 7, lane = rem & 63;
    int row = ftg * 16 + (lane & 15);
    int col = s * 32 + (lane >> 4) * 8;
    const float* Wsrc = (p == 0) ? Wt : (p == 1) ? Wp : Wg;
    short8 v8;
#pragma unroll
    for (int j = 0; j < 8; j++) v8[j] = f2bf(Wsrc[row * 256 + col + j]);
    *(short8*)(Wbf + (size_t)u * 8) = v8;
  } else if (u < 12288 + 4096) {
    int u2 = u - 12288;
    int cog = u2 >> 8, s = (u2 >> 6) & 3, lane = u2 & 63;
    int co = cog * 16 + (lane & 15);
    int ch = s * 32 + (lane >> 4) * 8;
    short8 v8;
#pragma unroll
    for (int j = 0; j < 8; j++) v8[j] = f2bf(Wz[co * 128 + ch + j]);
    *(short8*)(Wzbf + (size_t)u2 * 8) = v8;
  }
}

// ---------------- projections v5: pipelined transpose + frag-major W ----------
// Double-buffered fp32 tile: prefetch chunk ch+1 x-loads during ch's transpose
// phase; ONE barrier per chunk (disjoint buffers). Then 3 MFMA passes, A-frags
// loaded once, frag-major coalesced W loads.
__global__ void __launch_bounds__(256)
proj_kernel(const float* __restrict__ x, const short* __restrict__ Wbf,
            const float* __restrict__ bt, const float* __restrict__ bp,
            const float* __restrict__ bg,
            short* __restrict__ theta, short* __restrict__ Kb, short* __restrict__ gT) {
  __shared__ float tile[2][32][33];  // 8448 B
  __shared__ short Axy[32 * 264];    // 16896 B
  __shared__ short lds[5120];        // output staging
  int bx = blockIdx.x;
  int b = bx >> 7;
  int n0 = (bx & 127) << 5;
  int t = threadIdx.x, w = t >> 6, lane = t & 63, l15 = lane & 15, quad = lane >> 4;
  int r = t >> 5, cc = t & 31;

  const float* xb = x + (size_t)b * CIN * NSP;
  float rv[4];
  // preload chunk 0 and write tile[0]
#pragma unroll
  for (int k = 0; k < 4; k++) rv[k] = xb[(size_t)(r + 8 * k) * NSP + n0 + cc];
#pragma unroll
  for (int k = 0; k < 4; k++) tile[0][r + 8 * k][cc] = rv[k];

#pragma unroll
  for (int ch = 0; ch < 8; ch++) {
    __syncthreads();  // tile[ch&1] writes visible
    if (ch < 7) {
      int c0 = (ch + 1) * 32;
#pragma unroll
      for (int k = 0; k < 4; k++) rv[k] = xb[(size_t)(c0 + r + 8 * k) * NSP + n0 + cc];
    }
#pragma unroll
    for (int k = 0; k < 4; k++)
      Axy[(r + 8 * k) * 264 + ch * 32 + cc] = f2bf(tile[ch & 1][cc][r + 8 * k]);
    if (ch < 7) {
#pragma unroll
      for (int k = 0; k < 4; k++) tile[(ch + 1) & 1][r + 8 * k][cc] = rv[k];
    }
  }
  __syncthreads();

  // A-frags once, reused for all 3 projections
  short8 a[8];
  int ar = (w & 1) * 16 + l15;
#pragma unroll
  for (int s = 0; s < 8; s++)
    a[s] = *(const short8*)(Axy + ar * 264 + s * 32 + quad * 8);

  for (int p = 0; p < 3; p++) {
    const short* Wsrc = Wbf + p * 32768;
    f32x4 zero = {0.f, 0.f, 0.f, 0.f};
    f32x4 acc[4];
#pragma unroll
    for (int i = 0; i < 4; i++) acc[i] = zero;

#pragma unroll
    for (int s = 0; s < 8; s++) {
#pragma unroll
      for (int ft = 0; ft < 4; ft++) {
        int ftg = (w >> 1) * 4 + ft;
        short8 bfr = *(const short8*)(Wsrc + (ftg * 8 + s) * 512 + lane * 8);
        acc[ft] = __builtin_amdgcn_mfma_f32_16x16x32_bf16(a[s], bfr, acc[ft], 0, 0, 0);
      }
    }

    const float* bias = (p == 0) ? bt : (p == 1) ? bp : bg;
    if (p > 0) __syncthreads();
    if (p < 2) {
#pragma unroll
      for (int ft = 0; ft < 4; ft++) {
        int ftg = (w >> 1) * 4 + ft;
        float bv = bias[ftg * 16 + l15];
#pragma unroll
        for (int rr = 0; rr < 4; rr++) {
          int n = (w & 1) * 16 + quad * 4 + rr;
          lds[n * 136 + ftg * 16 + l15] = f2bf(acc[ft][rr] + bv);
        }
      }
      __syncthreads();
      short* dst = ((p == 0) ? theta : Kb) + (size_t)(b * NSP + n0) * FDIM;
#pragma unroll
      for (int i = 0; i < 2; i++) {
        int flat = t + 256 * i;
        int row = flat >> 4, ch = flat & 15;
        *(short8*)(dst + (size_t)row * FDIM + ch * 8) = *(const short8*)(lds + row * 136 + ch * 8);
      }
    } else {
#pragma unroll
      for (int ft = 0; ft < 4; ft++) {
        int ftg = (w >> 1) * 4 + ft;
        float bv = bias[ftg * 16 + l15];
#pragma unroll
        for (int rr = 0; rr < 4; rr++) {
          int n = (w & 1) * 16 + quad * 4 + rr;
          lds[(ftg * 16 + l15) * 40 + n] = f2bf(acc[ft][rr] + bv);
        }
      }
      __syncthreads();
      short* dst = gT + (size_t)b * FDIM * NSP + n0;
#pragma unroll
      for (int i = 0; i < 2; i++) {
        int flat = t + 256 * i;
        int f = flat >> 2, c = flat & 3;
        *(short8*)(dst + (size_t)f * NSP + c * 8) = *(const short8*)(lds + f * 40 + c * 8);
      }
    }
  }
}

// ---------------- flash attention v7 (verified 43.5us) + interleaved opart ----
// opart layout [b][row][kc][f]: row stride 512 shorts; lpart [b][row][kc].
__global__ void __launch_bounds__(256, 2)
flash_kernel(const short* __restrict__ thetab, const short* __restrict__ Kb,
             const short* __restrict__ gT, short* __restrict__ opart,
             float* __restrict__ lpart) {
  __shared__ __attribute__((aligned(16))) char smem[34816];
  short* Klds = (short*)smem;            // 16384 B: sub A +0, sub B +4096 shorts
  short* Vlds = (short*)(smem + 16384);  // 16384 B: sub A +0, sub B +4096 shorts

  const int bx = blockIdx.x;
  const int b  = bx >> 7;
  const int r  = bx & 127;
  const int q0 = (r >> 2) << 7;
  const int kc = r & 3;
  const int t = threadIdx.x, w = t >> 6, lane = t & 63;
  const int l31 = lane & 31, h = lane >> 5;
  const int qw = q0 + w * 32;

  const short* Qsrc = thetab + (size_t)b * NSP * FDIM;
  const short* Ksrc = Kb + (size_t)b * NSP * FDIM;
  const short* Vsrc = gT + (size_t)b * FDIM * NSP;

  short8 qf[8];
#pragma unroll
  for (int s = 0; s < 8; s++)
    qf[s] = *(const short8*)(Qsrc + (size_t)(qw + l31) * FDIM + s * 16 + h * 8);

  f32x16 O[4];
#pragma unroll
  for (int i = 0; i < 4; i++)
#pragma unroll
    for (int j = 0; j < 16; j++) O[i][j] = 0.f;
  float lsum = 0.f;

  const int kr0 = t >> 4, kcc0 = t & 15, kr1 = kr0 + 16;
  const int woK0 = kcc0 * 256 + ((kr0 ^ (kcc0 & 7)) * 8);
  const int woK1 = kcc0 * 256 + ((kr1 ^ (kcc0 & 7)) * 8);
  const int vf0 = t >> 2, vcc0 = t & 3, vf1 = 64 + (t >> 2);
  const int woV0 = vcc0 * 1024 + ((vf0 ^ (vcc0 & 3)) * 8);
  const int woV1 = vcc0 * 1024 + ((vf1 ^ (vcc0 & 3)) * 8);

  const int kA0 = kc << 10;
  short8 rKa0, rKa1, rKb0, rKb1, rVa0, rVa1, rVb0, rVb1;

  {
    rKa0 = *(const short8*)(Ksrc + (size_t)(kA0 + kr0) * FDIM + kcc0 * 8);
    rKa1 = *(const short8*)(Ksrc + (size_t)(kA0 + kr1) * FDIM + kcc0 * 8);
    rKb0 = *(const short8*)(Ksrc + (size_t)(kA0 + 32 + kr0) * FDIM + kcc0 * 8);
    rKb1 = *(const short8*)(Ksrc + (size_t)(kA0 + 32 + kr1) * FDIM + kcc0 * 8);
    rVa0 = *(const short8*)(Vsrc + (size_t)vf0 * NSP + kA0 + vcc0 * 8);
    rVa1 = *(const short8*)(Vsrc + (size_t)vf1 * NSP + kA0 + vcc0 * 8);
    rVb0 = *(const short8*)(Vsrc + (size_t)vf0 * NSP + kA0 + 32 + vcc0 * 8);
    rVb1 = *(const short8*)(Vsrc + (size_t)vf1 * NSP + kA0 + 32 + vcc0 * 8);
    *(short8*)(Klds + woK0) = rKa0;
    *(short8*)(Klds + woK1) = rKa1;
    *(short8*)(Klds + 4096 + woK0) = rKb0;
    *(short8*)(Klds + 4096 + woK1) = rKb1;
    *(short8*)(Vlds + woV0) = rVa0;
    *(short8*)(Vlds + woV1) = rVa1;
    *(short8*)(Vlds + 4096 + woV0) = rVb0;
    *(short8*)(Vlds + 4096 + woV1) = rVb1;
  }

#pragma unroll 2
  for (int it = 0; it < 16; ++it) {
    __syncthreads();
    if (it < 15) {
      int kn = kA0 + (it + 1) * 64;
      rKa0 = *(const short8*)(Ksrc + (size_t)(kn + kr0) * FDIM + kcc0 * 8);
      rKa1 = *(const short8*)(Ksrc + (size_t)(kn + kr1) * FDIM + kcc0 * 8);
      rKb0 = *(const short8*)(Ksrc + (size_t)(kn + 32 + kr0) * FDIM + kcc0 * 8);
      rKb1 = *(const short8*)(Ksrc + (size_t)(kn + 32 + kr1) * FDIM + kcc0 * 8);
      rVa0 = *(const short8*)(Vsrc + (size_t)vf0 * NSP + kn + vcc0 * 8);
      rVa1 = *(const short8*)(Vsrc + (size_t)vf1 * NSP + kn + vcc0 * 8);
      rVb0 = *(const short8*)(Vsrc + (size_t)vf0 * NSP + kn + 32 + vcc0 * 8);
      rVb1 = *(const short8*)(Vsrc + (size_t)vf1 * NSP + kn + 32 + vcc0 * 8);
    }

    f32x16 S0, S1;
#pragma unroll
    for (int j = 0; j < 16; j++) { S0[j] = 0.f; S1[j] = 0.f; }
    __builtin_amdgcn_s_setprio(1);
#pragma unroll
    for (int s = 0; s < 8; s++) {
      int c = 2 * s + h;
      const short* base = Klds + c * 256 + ((l31 ^ (c & 7)) * 8);
      short8 ak0 = *(const short8*)(base);
      short8 ak1 = *(const short8*)(base + 4096);
      S0 = __builtin_amdgcn_mfma_f32_32x32x16_bf16(ak0, qf[s], S0, 0, 0, 0);
      S1 = __builtin_amdgcn_mfma_f32_32x32x16_bf16(ak1, qf[s], S1, 0, 0, 0);
    }
    __builtin_amdgcn_s_setprio(0);

    short8 AfA[2], AfB[2];
#pragma unroll
    for (int sub = 0; sub < 2; sub++) {
      float p[16];
#pragma unroll
      for (int i = 0; i < 16; i++) p[i] = __expf(sub ? S1[i] : S0[i]);
      float t8[8];
#pragma unroll
      for (int i = 0; i < 8; i++) t8[i] = p[2 * i] + p[2 * i + 1];
      lsum += ((t8[0] + t8[1]) + (t8[2] + t8[3])) + ((t8[4] + t8[5]) + (t8[6] + t8[7]));

      uint32_t W[8];
#pragma unroll
      for (int j = 0; j < 8; j++)
        asm("v_cvt_pk_bf16_f32 %0, %1, %2" : "=v"(W[j]) : "v"(p[2 * j]), "v"(p[2 * j + 1]));
      asm("v_permlane32_swap_b32 %0, %1" : "+v"(W[0]), "+v"(W[2]));
      asm("v_permlane32_swap_b32 %0, %1" : "+v"(W[1]), "+v"(W[3]));
      asm("v_permlane32_swap_b32 %0, %1" : "+v"(W[4]), "+v"(W[6]));
      asm("v_permlane32_swap_b32 %0, %1" : "+v"(W[5]), "+v"(W[7]));
      union { short8 s; uint32_t u[4]; } u0, u1;
      u0.u[0] = W[0]; u0.u[1] = W[1]; u0.u[2] = W[2]; u0.u[3] = W[3];
      u1.u[0] = W[4]; u1.u[1] = W[5]; u1.u[2] = W[6]; u1.u[3] = W[7];
      if (sub) { AfB[0] = u0.s; AfB[1] = u1.s; }
      else     { AfA[0] = u0.s; AfA[1] = u1.s; }
    }

    __builtin_amdgcn_s_setprio(1);
#pragma unroll
    for (int ft = 0; ft < 4; ft++) {
#pragma unroll
      for (int tt = 0; tt < 2; tt++) {
        int c = tt * 2 + h;
        int off = c * 1024 + ft * 256 + ((l31 ^ (c & 3)) * 8);
        short8 bva = *(const short8*)(Vlds + off);
        O[ft] = __builtin_amdgcn_mfma_f32_32x32x16_bf16(AfA[tt], bva, O[ft], 0, 0, 0);
        short8 bvb = *(const short8*)(Vlds + off + 4096);
        O[ft] = __builtin_amdgcn_mfma_f32_32x32x16_bf16(AfB[tt], bvb, O[ft], 0, 0, 0);
      }
    }
    __builtin_amdgcn_s_setprio(0);

    __syncthreads();
    if (it < 15) {
      *(short8*)(Klds + woK0) = rKa0;
      *(short8*)(Klds + woK1) = rKa1;
      *(short8*)(Klds + 4096 + woK0) = rKb0;
      *(short8*)(Klds + 4096 + woK1) = rKb1;
      *(short8*)(Vlds + woV0) = rVa0;
      *(short8*)(Vlds + woV1) = rVa1;
      *(short8*)(Vlds + 4096 + woV0) = rVb0;
      *(short8*)(Vlds + 4096 + woV1) = rVb1;
    }
  }

  lsum += __shfl_xor(lsum, 32, 64);

  // epilogue: per-wave [32][136] transpose slice -> interleaved opart
  short* tr = (short*)smem + w * 32 * 136;
#pragma unroll
  for (int ft = 0; ft < 4; ft++) {
#pragma unroll
    for (int reg = 0; reg < 16; reg++) {
      int rowq = (reg & 3) + 8 * (reg >> 2) + 4 * h;
      tr[rowq * 136 + ft * 32 + l31] = f2bf(O[ft][reg]);
    }
  }
  short* od = opart + ((size_t)(b * NSP + qw) * 4 + kc) * FDIM;
#pragma unroll
  for (int i = 0; i < 8; i++) {
    int slot = lane + 64 * i;
    int row = slot >> 4, c = slot & 15;
    *(short8*)(od + (size_t)row * 4 * FDIM + c * 8) = *(const short8*)(tr + row * 136 + c * 8);
  }
  if (h == 0) lpart[((size_t)b * NSP + qw + l31) * 4 + kc] = lsum;
}

// ---------------- z projection v4: contiguous split-K combine ----------------
__global__ void __launch_bounds__(256)
zproj_kernel(const short* __restrict__ opart, const float* __restrict__ lpart,
             const short* __restrict__ Wzbf, const float* __restrict__ bz,
             short* __restrict__ zb, float* __restrict__ sums) {
  __shared__ short Alds[32 * 136];
  __shared__ short ldsT[128 * 40];
  __shared__ float Linv[32];
  __shared__ float wsum[4][2];
  int bx = blockIdx.x;
  int b = bx >> 7;
  int n0 = (bx & 127) << 5;
  int ch0 = blockIdx.y * 128;
  int t = threadIdx.x, w = t >> 6, lane = t & 63, l15 = lane & 15, quad = lane >> 4;

  // phase 0: per-row denominators — ONE contiguous float4 per row
  if (t < 32) {
    f32x4 L4 = *(const f32x4*)(lpart + ((size_t)b * NSP + n0 + t) * 4);
    Linv[t] = 1.0f / ((L4[0] + L4[1]) + (L4[2] + L4[3]));
  }
  __syncthreads();

  // phase 1: contiguous split-K combine -> normalized bf16 A-tile in LDS
#pragma unroll
  for (int iter = 0; iter < 2; iter++) {
    int i = t + 256 * iter;
    int row = i >> 4, c16 = i & 15;
    const short* base = opart + ((size_t)(b * NSP + n0 + row) * 4) * FDIM + c16 * 8;
    float accv[8] = {0, 0, 0, 0, 0, 0, 0, 0};
#pragma unroll
    for (int kcc = 0; kcc < 4; kcc++) {
      short8 v = *(const short8*)(base + kcc * FDIM);
#pragma unroll
      for (int j = 0; j < 8; j++) accv[j] += bf2f(v[j]);
    }
    float inv = Linv[row];
    short8 av;
#pragma unroll
    for (int j = 0; j < 8; j++) av[j] = f2bf(accv[j] * inv);
    *(short8*)(Alds + row * 136 + c16 * 8) = av;
  }
  __syncthreads();

  // phase 2: a-frags from LDS, MFMA vs frag-major Wz
  short8 a[4];
#pragma unroll
  for (int s = 0; s < 4; s++)
    a[s] = *(const short8*)(Alds + ((w & 1) * 16 + l15) * 136 + s * 32 + quad * 8);

  f32x4 zero = {0.f, 0.f, 0.f, 0.f};
  f32x4 acc[4];
#pragma unroll
  for (int i = 0; i < 4; i++) acc[i] = zero;
#pragma unroll
  for (int s = 0; s < 4; s++) {
#pragma unroll
    for (int ct = 0; ct < 4; ct++) {
      int cog = blockIdx.y * 8 + (w >> 1) * 4 + ct;
      short8 bfr = *(const short8*)(Wzbf + cog * 2048 + s * 512 + lane * 8);
      acc[ct] = __builtin_amdgcn_mfma_f32_16x16x32_bf16(a[s], bfr, acc[ct], 0, 0, 0);
    }
  }

  float s1 = 0.0f, s2 = 0.0f;
#pragma unroll
  for (int ct = 0; ct < 4; ct++) {
    int cg = (w >> 1) * 64 + ct * 16 + l15;
    float bv = bz[ch0 + cg];
#pragma unroll
    for (int rr = 0; rr < 4; rr++) {
      float v = acc[ct][rr] + bv;
      s1 += v; s2 += v * v;
      ldsT[cg * 40 + (w & 1) * 16 + quad * 4 + rr] = f2bf(v);
    }
  }
#pragma unroll
  for (int off = 32; off >= 1; off >>= 1) {
    s1 += __shfl_xor(s1, off, 64);
    s2 += __shfl_xor(s2, off, 64);
  }
  if (lane == 0) { wsum[w][0] = s1; wsum[w][1] = s2; }
  __syncthreads();
  if (t == 0) {
    atomicAdd(&sums[b * 2],     wsum[0][0] + wsum[1][0] + wsum[2][0] + wsum[3][0]);
    atomicAdd(&sums[b * 2 + 1], wsum[0][1] + wsum[1][1] + wsum[2][1] + wsum[3][1]);
  }
  short* dst = zb + (size_t)b * CIN * NSP + (size_t)ch0 * NSP + n0;
#pragma unroll
  for (int i = 0; i < 2; i++) {
    int flat = t + 256 * i;
    int c = flat >> 2, ch = flat & 3;
    *(short8*)(dst + (size_t)c * NSP + ch * 8) = *(const short8*)(ldsT + c * 40 + ch * 8);
  }
}

// ---------------- LayerNorm + affine + residual (vectorized) ----------------
__global__ void __launch_bounds__(256)
finalize_kernel(const short* __restrict__ zbuf, const float* __restrict__ x,
                const float* __restrict__ lnw, const float* __restrict__ lnb,
                const float* __restrict__ sums, float* __restrict__ out) {
  int gid = blockIdx.x * 256 + threadIdx.x;
  size_t e0 = (size_t)gid * 8;
  int b = (int)(e0 >> 20);  // CIN*NSP = 2^20
  size_t ib = e0 & ((size_t)(1u << 20) - 1);
  float mean = sums[b * 2] * (1.0f / 1048576.0f);
  float var = sums[b * 2 + 1] * (1.0f / 1048576.0f) - mean * mean;
  float rs = rsqrtf(var + EPS);
  short8 zv = *(const short8*)(zbuf + e0);
  f32x4 xv0 = *(const f32x4*)(x + e0),   xv1 = *(const f32x4*)(x + e0 + 4);
  f32x4 wv0 = *(const f32x4*)(lnw + ib), wv1 = *(const f32x4*)(lnw + ib + 4);
  f32x4 bv0 = *(const f32x4*)(lnb + ib), bv1 = *(const f32x4*)(lnb + ib + 4);
  f32x4 o0, o1;
#pragma unroll
  for (int k = 0; k < 4; k++) {
    o0[k] = (bf2f(zv[k]) - mean) * rs * wv0[k] + bv0[k] + xv0[k];
    o1[k] = (bf2f(zv[k + 4]) - mean) * rs * wv1[k] + bv1[k] + xv1[k];
  }
  *(f32x4*)(out + e0) = o0;
  *(f32x4*)(out + e0 + 4) = o1;
}

extern "C" void kernel_launch(void* const* d_in, const int* in_sizes, int n_in,
                              void* d_out, int out_size, void* d_ws, size_t ws_size,
                              hipStream_t stream) {
  const float* x   = (const float*)d_in[0];
  const float* Wg  = (const float*)d_in[1];
  const float* bg  = (const float*)d_in[2];
  const float* Wt  = (const float*)d_in[3];
  const float* bt  = (const float*)d_in[4];
  const float* Wp  = (const float*)d_in[5];
  const float* bp  = (const float*)d_in[6];
  const float* Wz  = (const float*)d_in[7];
  const float* bz  = (const float*)d_in[8];
  const float* lnw = (const float*)d_in[9];
  const float* lnb = (const float*)d_in[10];
  float* out = (float*)d_out;

  // Workspace (~29.9 MB, lifetime overlaps):
  //  [0, 196608)           Wbf (frag-major)
  //  [196608, 262144)      Wzbf (frag-major)
  //  [262144, 17039360)    opart 16 MB (interleaved [b][row][kc][f])
  //  [17039360, 17301504)  lpart 256 KB (interleaved [b][row][kc])
  //  [17301504, 21495808)  thetab 4 MB \__ zb (8 MB) overlays after flash
  //  [21495808, 25690112)  Kb 4 MB     /
  //  [25690112, 29884416)  gT 4 MB
  //  [29884416, +32)       sums (8 floats, zeroed by prep_w, atomically accumulated)
  char* ws = (char*)d_ws;
  short* Wbf    = (short*)(ws);
  short* Wzbf   = (short*)(ws + 196608);
  short* opart  = (short*)(ws + 262144);
  float* lpart  = (float*)(ws + 17039360);
  short* thetab = (short*)(ws + 17301504);
  short* Kb     = (short*)(ws + 21495808);
  short* gT     = (short*)(ws + 25690112);
  short* zb     = (short*)(ws + 17301504);
  float* sums   = (float*)(ws + 29884416);

  prep_w<<<64, 256, 0, stream>>>(Wg, Wt, Wp, Wz, Wbf, Wzbf, sums);
  proj_kernel<<<512, 256, 0, stream>>>(x, Wbf, bt, bp, bg, thetab, Kb, gT);
  flash_kernel<<<512, 256, 0, stream>>>(thetab, Kb, gT, opart, lpart);
  zproj_kernel<<<dim3(512, 2), 256, 0, stream>>>(opart, lpart, Wzbf, bz, zb, sums);
  finalize_kernel<<<2048, 256, 0, stream>>>(zb, x, lnw, lnb, sums, out);
}

// Round 13
// 179.963 us; speedup vs baseline: 1.0827x; 1.0827x over previous
//
#include <hip/hip_runtime.h>
#include <stdint.h>

#define CIN 256
#define FDIM 128
#define NSP 4096
#define EPS 1e-5f

typedef __attribute__((ext_vector_type(8))) short short8;
typedef __attribute__((ext_vector_type(4))) float f32x4;
typedef __attribute__((ext_vector_type(16))) float f32x16;

__device__ __forceinline__ short f2bf(float f) {
  union { float f; uint32_t u; } v; v.f = f;
  uint32_t r = v.u + 0x7fffu + ((v.u >> 16) & 1u);
  return (short)(r >> 16);
}
__device__ __forceinline__ float bf2f(short h) {
  union { uint32_t u; float f; } v; v.u = ((uint32_t)(uint16_t)h) << 16;
  return v.f;
}

// ---------------- tiny prep: weights -> FRAG-MAJOR bf16, zero sums ----------------
__global__ void prep_w(const float* __restrict__ Wg, const float* __restrict__ Wt,
                       const float* __restrict__ Wp, const float* __restrict__ Wz,
                       short* __restrict__ Wbf, short* __restrict__ Wzbf,
                       float* __restrict__ sums) {
  int u = blockIdx.x * 256 + threadIdx.x;
  if (u < 8 && blockIdx.x == 0) sums[u] = 0.f;
  if (u < 12288) {
    int p = u >> 12;
    int rem = u & 4095;
    int ftg = rem >> 9, s = (rem >> 6) & 7, lane = rem & 63;
    int row = ftg * 16 + (lane & 15);
    int col = s * 32 + (lane >> 4) * 8;
    const float* Wsrc = (p == 0) ? Wt : (p == 1) ? Wp : Wg;
    short8 v8;
#pragma unroll
    for (int j = 0; j < 8; j++) v8[j] = f2bf(Wsrc[row * 256 + col + j]);
    *(short8*)(Wbf + (size_t)u * 8) = v8;
  } else if (u < 12288 + 4096) {
    int u2 = u - 12288;
    int cog = u2 >> 8, s = (u2 >> 6) & 3, lane = u2 & 63;
    int co = cog * 16 + (lane & 15);
    int ch = s * 32 + (lane >> 4) * 8;
    short8 v8;
#pragma unroll
    for (int j = 0; j < 8; j++) v8[j] = f2bf(Wz[co * 128 + ch + j]);
    *(short8*)(Wzbf + (size_t)u2 * 8) = v8;
  }
}

// ---------------- projections v4: fused x-transpose + all 3 projections ----------
__global__ void __launch_bounds__(256)
proj_kernel(const float* __restrict__ x, const short* __restrict__ Wbf,
            const float* __restrict__ bt, const float* __restrict__ bp,
            const float* __restrict__ bg,
            short* __restrict__ theta, short* __restrict__ Kb, short* __restrict__ gT) {
  __shared__ float tile[32][33];   // 4224 B
  __shared__ short Axy[32 * 264];  // 16896 B
  __shared__ short lds[5120];      // output staging: max(32*136, 128*40)
  int bx = blockIdx.x;
  int b = bx >> 7;
  int n0 = (bx & 127) << 5;
  int t = threadIdx.x, w = t >> 6, lane = t & 63, l15 = lane & 15, quad = lane >> 4;
  int r = t >> 5, cc = t & 31;

  // stage + transpose x tile: 8 chunks of 32 channels
  const float* xb = x + (size_t)b * CIN * NSP;
#pragma unroll
  for (int ch = 0; ch < 8; ch++) {
    int c0 = ch * 32;
#pragma unroll
    for (int k = 0; k < 4; k++)
      tile[r + 8 * k][cc] = xb[(size_t)(c0 + r + 8 * k) * NSP + n0 + cc];
    __syncthreads();
#pragma unroll
    for (int k = 0; k < 4; k++)
      Axy[(r + 8 * k) * 264 + c0 + cc] = f2bf(tile[cc][r + 8 * k]);
    __syncthreads();
  }

  // A-frags once, reused for all 3 projections
  short8 a[8];
  int ar = (w & 1) * 16 + l15;
#pragma unroll
  for (int s = 0; s < 8; s++)
    a[s] = *(const short8*)(Axy + ar * 264 + s * 32 + quad * 8);

  for (int p = 0; p < 3; p++) {
    const short* Wsrc = Wbf + p * 32768;  // frag-major block for this projection
    f32x4 zero = {0.f, 0.f, 0.f, 0.f};
    f32x4 acc[4];
#pragma unroll
    for (int i = 0; i < 4; i++) acc[i] = zero;

#pragma unroll
    for (int s = 0; s < 8; s++) {
#pragma unroll
      for (int ft = 0; ft < 4; ft++) {
        int ftg = (w >> 1) * 4 + ft;
        short8 bfr = *(const short8*)(Wsrc + (ftg * 8 + s) * 512 + lane * 8);
        acc[ft] = __builtin_amdgcn_mfma_f32_16x16x32_bf16(a[s], bfr, acc[ft], 0, 0, 0);
      }
    }

    const float* bias = (p == 0) ? bt : (p == 1) ? bp : bg;
    if (p > 0) __syncthreads();  // previous p's store-phase reads of lds done
    if (p < 2) {
#pragma unroll
      for (int ft = 0; ft < 4; ft++) {
        int ftg = (w >> 1) * 4 + ft;
        float bv = bias[ftg * 16 + l15];
#pragma unroll
        for (int rr = 0; rr < 4; rr++) {
          int n = (w & 1) * 16 + quad * 4 + rr;
          lds[n * 136 + ftg * 16 + l15] = f2bf(acc[ft][rr] + bv);
        }
      }
      __syncthreads();
      short* dst = ((p == 0) ? theta : Kb) + (size_t)(b * NSP + n0) * FDIM;
#pragma unroll
      for (int i = 0; i < 2; i++) {
        int flat = t + 256 * i;
        int row = flat >> 4, ch = flat & 15;
        *(short8*)(dst + (size_t)row * FDIM + ch * 8) = *(const short8*)(lds + row * 136 + ch * 8);
      }
    } else {
#pragma unroll
      for (int ft = 0; ft < 4; ft++) {
        int ftg = (w >> 1) * 4 + ft;
        float bv = bias[ftg * 16 + l15];
#pragma unroll
        for (int rr = 0; rr < 4; rr++) {
          int n = (w & 1) * 16 + quad * 4 + rr;
          lds[(ftg * 16 + l15) * 40 + n] = f2bf(acc[ft][rr] + bv);
        }
      }
      __syncthreads();
      short* dst = gT + (size_t)b * FDIM * NSP + n0;
#pragma unroll
      for (int i = 0; i < 2; i++) {
        int flat = t + 256 * i;
        int f = flat >> 2, c = flat & 3;
        *(short8*)(dst + (size_t)f * NSP + c * 8) = *(const short8*)(lds + f * 40 + c * 8);
      }
    }
  }
}

// ---------------- flash attention v7: single-buffer conflict-free chunk-major LDS ----
// (verified local optimum: 2 blocks/CU, 32 q/wave, ~43.5 us; R8/R10 counters identical)
__global__ void __launch_bounds__(256, 2)
flash_kernel(const short* __restrict__ thetab, const short* __restrict__ Kb,
             const short* __restrict__ gT, short* __restrict__ opart,
             float* __restrict__ lpart) {
  __shared__ __attribute__((aligned(16))) char smem[34816];
  short* Klds = (short*)smem;            // 16384 B: sub A +0, sub B +4096 shorts
  short* Vlds = (short*)(smem + 16384);  // 16384 B: sub A +0, sub B +4096 shorts

  const int bx = blockIdx.x;
  const int b  = bx >> 7;
  const int r  = bx & 127;
  const int q0 = (r >> 2) << 7;
  const int kc = r & 3;
  const int t = threadIdx.x, w = t >> 6, lane = t & 63;
  const int l31 = lane & 31, h = lane >> 5;
  const int qw = q0 + w * 32;

  const short* Qsrc = thetab + (size_t)b * NSP * FDIM;
  const short* Ksrc = Kb + (size_t)b * NSP * FDIM;
  const short* Vsrc = gT + (size_t)b * FDIM * NSP;

  short8 qf[8];
#pragma unroll
  for (int s = 0; s < 8; s++)
    qf[s] = *(const short8*)(Qsrc + (size_t)(qw + l31) * FDIM + s * 16 + h * 8);

  f32x16 O[4];
#pragma unroll
  for (int i = 0; i < 4; i++)
#pragma unroll
    for (int j = 0; j < 16; j++) O[i][j] = 0.f;
  float lsum = 0.f;

  const int kr0 = t >> 4, kcc0 = t & 15, kr1 = kr0 + 16;
  const int woK0 = kcc0 * 256 + ((kr0 ^ (kcc0 & 7)) * 8);
  const int woK1 = kcc0 * 256 + ((kr1 ^ (kcc0 & 7)) * 8);
  const int vf0 = t >> 2, vcc0 = t & 3, vf1 = 64 + (t >> 2);
  const int woV0 = vcc0 * 1024 + ((vf0 ^ (vcc0 & 3)) * 8);
  const int woV1 = vcc0 * 1024 + ((vf1 ^ (vcc0 & 3)) * 8);

  const int kA0 = kc << 10;
  short8 rKa0, rKa1, rKb0, rKb1, rVa0, rVa1, rVb0, rVb1;

  {
    rKa0 = *(const short8*)(Ksrc + (size_t)(kA0 + kr0) * FDIM + kcc0 * 8);
    rKa1 = *(const short8*)(Ksrc + (size_t)(kA0 + kr1) * FDIM + kcc0 * 8);
    rKb0 = *(const short8*)(Ksrc + (size_t)(kA0 + 32 + kr0) * FDIM + kcc0 * 8);
    rKb1 = *(const short8*)(Ksrc + (size_t)(kA0 + 32 + kr1) * FDIM + kcc0 * 8);
    rVa0 = *(const short8*)(Vsrc + (size_t)vf0 * NSP + kA0 + vcc0 * 8);
    rVa1 = *(const short8*)(Vsrc + (size_t)vf1 * NSP + kA0 + vcc0 * 8);
    rVb0 = *(const short8*)(Vsrc + (size_t)vf0 * NSP + kA0 + 32 + vcc0 * 8);
    rVb1 = *(const short8*)(Vsrc + (size_t)vf1 * NSP + kA0 + 32 + vcc0 * 8);
    *(short8*)(Klds + woK0) = rKa0;
    *(short8*)(Klds + woK1) = rKa1;
    *(short8*)(Klds + 4096 + woK0) = rKb0;
    *(short8*)(Klds + 4096 + woK1) = rKb1;
    *(short8*)(Vlds + woV0) = rVa0;
    *(short8*)(Vlds + woV1) = rVa1;
    *(short8*)(Vlds + 4096 + woV0) = rVb0;
    *(short8*)(Vlds + 4096 + woV1) = rVb1;
  }

#pragma unroll 2
  for (int it = 0; it < 16; ++it) {
    __syncthreads();  // staged writes for tile `it` visible
    if (it < 15) {
      int kn = kA0 + (it + 1) * 64;
      rKa0 = *(const short8*)(Ksrc + (size_t)(kn + kr0) * FDIM + kcc0 * 8);
      rKa1 = *(const short8*)(Ksrc + (size_t)(kn + kr1) * FDIM + kcc0 * 8);
      rKb0 = *(const short8*)(Ksrc + (size_t)(kn + 32 + kr0) * FDIM + kcc0 * 8);
      rKb1 = *(const short8*)(Ksrc + (size_t)(kn + 32 + kr1) * FDIM + kcc0 * 8);
      rVa0 = *(const short8*)(Vsrc + (size_t)vf0 * NSP + kn + vcc0 * 8);
      rVa1 = *(const short8*)(Vsrc + (size_t)vf1 * NSP + kn + vcc0 * 8);
      rVb0 = *(const short8*)(Vsrc + (size_t)vf0 * NSP + kn + 32 + vcc0 * 8);
      rVb1 = *(const short8*)(Vsrc + (size_t)vf1 * NSP + kn + 32 + vcc0 * 8);
    }

    f32x16 S0, S1;
#pragma unroll
    for (int j = 0; j < 16; j++) { S0[j] = 0.f; S1[j] = 0.f; }
    __builtin_amdgcn_s_setprio(1);
#pragma unroll
    for (int s = 0; s < 8; s++) {
      int c = 2 * s + h;
      const short* base = Klds + c * 256 + ((l31 ^ (c & 7)) * 8);
      short8 ak0 = *(const short8*)(base);
      short8 ak1 = *(const short8*)(base + 4096);
      S0 = __builtin_amdgcn_mfma_f32_32x32x16_bf16(ak0, qf[s], S0, 0, 0, 0);
      S1 = __builtin_amdgcn_mfma_f32_32x32x16_bf16(ak1, qf[s], S1, 0, 0, 0);
    }
    __builtin_amdgcn_s_setprio(0);

    short8 AfA[2], AfB[2];
#pragma unroll
    for (int sub = 0; sub < 2; sub++) {
      float p[16];
#pragma unroll
      for (int i = 0; i < 16; i++) p[i] = __expf(sub ? S1[i] : S0[i]);
      float t8[8];
#pragma unroll
      for (int i = 0; i < 8; i++) t8[i] = p[2 * i] + p[2 * i + 1];
      lsum += ((t8[0] + t8[1]) + (t8[2] + t8[3])) + ((t8[4] + t8[5]) + (t8[6] + t8[7]));

      uint32_t W[8];
#pragma unroll
      for (int j = 0; j < 8; j++)
        asm("v_cvt_pk_bf16_f32 %0, %1, %2" : "=v"(W[j]) : "v"(p[2 * j]), "v"(p[2 * j + 1]));
      asm("v_permlane32_swap_b32 %0, %1" : "+v"(W[0]), "+v"(W[2]));
      asm("v_permlane32_swap_b32 %0, %1" : "+v"(W[1]), "+v"(W[3]));
      asm("v_permlane32_swap_b32 %0, %1" : "+v"(W[4]), "+v"(W[6]));
      asm("v_permlane32_swap_b32 %0, %1" : "+v"(W[5]), "+v"(W[7]));
      union { short8 s; uint32_t u[4]; } u0, u1;
      u0.u[0] = W[0]; u0.u[1] = W[1]; u0.u[2] = W[2]; u0.u[3] = W[3];
      u1.u[0] = W[4]; u1.u[1] = W[5]; u1.u[2] = W[6]; u1.u[3] = W[7];
      if (sub) { AfB[0] = u0.s; AfB[1] = u1.s; }
      else     { AfA[0] = u0.s; AfA[1] = u1.s; }
    }

    __builtin_amdgcn_s_setprio(1);
#pragma unroll
    for (int ft = 0; ft < 4; ft++) {
#pragma unroll
      for (int tt = 0; tt < 2; tt++) {
        int c = tt * 2 + h;
        int off = c * 1024 + ft * 256 + ((l31 ^ (c & 3)) * 8);
        short8 bva = *(const short8*)(Vlds + off);
        O[ft] = __builtin_amdgcn_mfma_f32_32x32x16_bf16(AfA[tt], bva, O[ft], 0, 0, 0);
        short8 bvb = *(const short8*)(Vlds + off + 4096);
        O[ft] = __builtin_amdgcn_mfma_f32_32x32x16_bf16(AfB[tt], bvb, O[ft], 0, 0, 0);
      }
    }
    __builtin_amdgcn_s_setprio(0);

    __syncthreads();  // all reads of tile `it` done; safe to overwrite
    if (it < 15) {
      *(short8*)(Klds + woK0) = rKa0;
      *(short8*)(Klds + woK1) = rKa1;
      *(short8*)(Klds + 4096 + woK0) = rKb0;
      *(short8*)(Klds + 4096 + woK1) = rKb1;
      *(short8*)(Vlds + woV0) = rVa0;
      *(short8*)(Vlds + woV1) = rVa1;
      *(short8*)(Vlds + 4096 + woV0) = rVb0;
      *(short8*)(Vlds + 4096 + woV1) = rVb1;
    }
  }

  lsum += __shfl_xor(lsum, 32, 64);

  // epilogue: per-wave [32][136] transpose slice -> contiguous opart rows
  short* tr = (short*)smem + w * 32 * 136;
#pragma unroll
  for (int ft = 0; ft < 4; ft++) {
#pragma unroll
    for (int reg = 0; reg < 16; reg++) {
      int rowq = (reg & 3) + 8 * (reg >> 2) + 4 * h;
      tr[rowq * 136 + ft * 32 + l31] = f2bf(O[ft][reg]);
    }
  }
  short* od = opart + ((size_t)(kc * 4 + b) * NSP + qw) * FDIM;
#pragma unroll
  for (int i = 0; i < 8; i++) {
    int slot = lane + 64 * i;
    int row = slot >> 4, c = slot & 15;
    *(short8*)(od + (size_t)row * FDIM + c * 8) = *(const short8*)(tr + row * 136 + c * 8);
  }
  if (h == 0) lpart[(size_t)(kc * 4 + b) * NSP + qw + l31] = lsum;
}

// ---------------- z projection v3: coalesced combine + frag-major Wz loads ----------
__global__ void __launch_bounds__(256)
zproj_kernel(const short* __restrict__ opart, const float* __restrict__ lpart,
             const short* __restrict__ Wzbf, const float* __restrict__ bz,
             short* __restrict__ zb, float* __restrict__ sums) {
  __shared__ short Alds[32 * 136];
  __shared__ short ldsT[128 * 40];
  __shared__ float Linv[32];
  __shared__ float wsum[4][2];
  int bx = blockIdx.x;
  int b = bx >> 7;
  int n0 = (bx & 127) << 5;
  int ch0 = blockIdx.y * 128;
  int t = threadIdx.x, w = t >> 6, lane = t & 63, l15 = lane & 15, quad = lane >> 4;

  // phase 0: per-row denominators (coalesced 32-float loads per partition)
  if (t < 32) {
    float L = 0.f;
#pragma unroll
    for (int kcc = 0; kcc < 4; kcc++) L += lpart[(size_t)(kcc * 4 + b) * NSP + n0 + t];
    Linv[t] = 1.0f / L;
  }
  __syncthreads();

  // phase 1: coalesced split-K combine -> normalized bf16 A-tile in LDS
#pragma unroll
  for (int iter = 0; iter < 2; iter++) {
    int i = t + 256 * iter;
    int row = i >> 4, c16 = i & 15;
    const short* base = opart + ((size_t)b * NSP + n0 + row) * FDIM + c16 * 8;
    float accv[8] = {0, 0, 0, 0, 0, 0, 0, 0};
#pragma unroll
    for (int kcc = 0; kcc < 4; kcc++) {
      short8 v = *(const short8*)(base + (size_t)kcc * 4 * NSP * FDIM);
#pragma unroll
      for (int j = 0; j < 8; j++) accv[j] += bf2f(v[j]);
    }
    float inv = Linv[row];
    short8 av;
#pragma unroll
    for (int j = 0; j < 8; j++) av[j] = f2bf(accv[j] * inv);
    *(short8*)(Alds + row * 136 + c16 * 8) = av;
  }
  __syncthreads();

  // phase 2: a-frags from LDS, MFMA vs frag-major Wz
  short8 a[4];
#pragma unroll
  for (int s = 0; s < 4; s++)
    a[s] = *(const short8*)(Alds + ((w & 1) * 16 + l15) * 136 + s * 32 + quad * 8);

  f32x4 zero = {0.f, 0.f, 0.f, 0.f};
  f32x4 acc[4];
#pragma unroll
  for (int i = 0; i < 4; i++) acc[i] = zero;
#pragma unroll
  for (int s = 0; s < 4; s++) {
#pragma unroll
    for (int ct = 0; ct < 4; ct++) {
      int cog = blockIdx.y * 8 + (w >> 1) * 4 + ct;
      short8 bfr = *(const short8*)(Wzbf + cog * 2048 + s * 512 + lane * 8);
      acc[ct] = __builtin_amdgcn_mfma_f32_16x16x32_bf16(a[s], bfr, acc[ct], 0, 0, 0);
    }
  }

  float s1 = 0.0f, s2 = 0.0f;
#pragma unroll
  for (int ct = 0; ct < 4; ct++) {
    int cg = (w >> 1) * 64 + ct * 16 + l15;
    float bv = bz[ch0 + cg];
#pragma unroll
    for (int rr = 0; rr < 4; rr++) {
      float v = acc[ct][rr] + bv;
      s1 += v; s2 += v * v;
      ldsT[cg * 40 + (w & 1) * 16 + quad * 4 + rr] = f2bf(v);
    }
  }
#pragma unroll
  for (int off = 32; off >= 1; off >>= 1) {
    s1 += __shfl_xor(s1, off, 64);
    s2 += __shfl_xor(s2, off, 64);
  }
  if (lane == 0) { wsum[w][0] = s1; wsum[w][1] = s2; }
  __syncthreads();
  if (t == 0) {
    atomicAdd(&sums[b * 2],     wsum[0][0] + wsum[1][0] + wsum[2][0] + wsum[3][0]);
    atomicAdd(&sums[b * 2 + 1], wsum[0][1] + wsum[1][1] + wsum[2][1] + wsum[3][1]);
  }
  short* dst = zb + (size_t)b * CIN * NSP + (size_t)ch0 * NSP + n0;
#pragma unroll
  for (int i = 0; i < 2; i++) {
    int flat = t + 256 * i;
    int c = flat >> 2, ch = flat & 3;
    *(short8*)(dst + (size_t)c * NSP + ch * 8) = *(const short8*)(ldsT + c * 40 + ch * 8);
  }
}

// ---------------- LayerNorm + affine + residual (vectorized) ----------------
__global__ void __launch_bounds__(256)
finalize_kernel(const short* __restrict__ zbuf, const float* __restrict__ x,
                const float* __restrict__ lnw, const float* __restrict__ lnb,
                const float* __restrict__ sums, float* __restrict__ out) {
  int gid = blockIdx.x * 256 + threadIdx.x;
  size_t e0 = (size_t)gid * 8;
  int b = (int)(e0 >> 20);  // CIN*NSP = 2^20
  size_t ib = e0 & ((size_t)(1u << 20) - 1);
  float mean = sums[b * 2] * (1.0f / 1048576.0f);
  float var = sums[b * 2 + 1] * (1.0f / 1048576.0f) - mean * mean;
  float rs = rsqrtf(var + EPS);
  short8 zv = *(const short8*)(zbuf + e0);
  f32x4 xv0 = *(const f32x4*)(x + e0),   xv1 = *(const f32x4*)(x + e0 + 4);
  f32x4 wv0 = *(const f32x4*)(lnw + ib), wv1 = *(const f32x4*)(lnw + ib + 4);
  f32x4 bv0 = *(const f32x4*)(lnb + ib), bv1 = *(const f32x4*)(lnb + ib + 4);
  f32x4 o0, o1;
#pragma unroll
  for (int k = 0; k < 4; k++) {
    o0[k] = (bf2f(zv[k]) - mean) * rs * wv0[k] + bv0[k] + xv0[k];
    o1[k] = (bf2f(zv[k + 4]) - mean) * rs * wv1[k] + bv1[k] + xv1[k];
  }
  *(f32x4*)(out + e0) = o0;
  *(f32x4*)(out + e0 + 4) = o1;
}

extern "C" void kernel_launch(void* const* d_in, const int* in_sizes, int n_in,
                              void* d_out, int out_size, void* d_ws, size_t ws_size,
                              hipStream_t stream) {
  const float* x   = (const float*)d_in[0];
  const float* Wg  = (const float*)d_in[1];
  const float* bg  = (const float*)d_in[2];
  const float* Wt  = (const float*)d_in[3];
  const float* bt  = (const float*)d_in[4];
  const float* Wp  = (const float*)d_in[5];
  const float* bp  = (const float*)d_in[6];
  const float* Wz  = (const float*)d_in[7];
  const float* bz  = (const float*)d_in[8];
  const float* lnw = (const float*)d_in[9];
  const float* lnb = (const float*)d_in[10];
  float* out = (float*)d_out;

  // Workspace (~29.9 MB, lifetime overlaps):
  //  [0, 196608)           Wbf (frag-major)
  //  [196608, 262144)      Wzbf (frag-major)
  //  [262144, 17039360)    opart 16 MB ([kc*4+b][row][f], contiguous rows)
  //  [17039360, 17301504)  lpart 256 KB
  //  [17301504, 21495808)  thetab 4 MB \__ zb (8 MB) overlays after flash
  //  [21495808, 25690112)  Kb 4 MB     /
  //  [25690112, 29884416)  gT 4 MB
  //  [29884416, +32)       sums (8 floats, zeroed by prep_w, atomically accumulated)
  char* ws = (char*)d_ws;
  short* Wbf    = (short*)(ws);
  short* Wzbf   = (short*)(ws + 196608);
  short* opart  = (short*)(ws + 262144);
  float* lpart  = (float*)(ws + 17039360);
  short* thetab = (short*)(ws + 17301504);
  short* Kb     = (short*)(ws + 21495808);
  short* gT     = (short*)(ws + 25690112);
  short* zb     = (short*)(ws + 17301504);
  float* sums   = (float*)(ws + 29884416);

  prep_w<<<64, 256, 0, stream>>>(Wg, Wt, Wp, Wz, Wbf, Wzbf, sums);
  proj_kernel<<<512, 256, 0, stream>>>(x, Wbf, bt, bp, bg, thetab, Kb, gT);
  flash_kernel<<<512, 256, 0, stream>>>(thetab, Kb, gT, opart, lpart);
  zproj_kernel<<<dim3(512, 2), 256, 0, stream>>>(opart, lpart, Wzbf, bz, zb, sums);
  finalize_kernel<<<2048, 256, 0, stream>>>(zb, x, lnw, lnb, sums, out);
}